// Round 2
// baseline (95.508 us; speedup 1.0000x reference)
//
#include <hip/hip_runtime.h>
#include <hip/hip_bf16.h>
#include <cstdint>

#define BATCH   16384
#define INDIM   512
#define OUTDIM  128
#define NINT    31
#define BM      64
#define THREADS 256

// ws layout (bytes)
#define WS_WBF    0u        // bf16 [64][512]  (rows 62,63 zero-pad)
#define WS_LEAFT  65536u    // bf16 [128 col][64 node] (node 63 zero)
#define WS_BIAS   81920u    // f32 [64] (62,63 zero)
#define WS_GSM0   82176u    // f32 [31]
#define WS_GSM1   82432u    // f32 [31]

typedef __attribute__((ext_vector_type(8))) short s8v;   // 8 bf16
typedef __attribute__((ext_vector_type(4))) float f4v;   // MFMA acc

__device__ __forceinline__ short bfs(float f) {
    return (short)__builtin_bit_cast(unsigned short, __float2bfloat16(f));
}
__device__ __forceinline__ unsigned int pk2(float lo, float hi) {
    return (unsigned int)(unsigned short)bfs(lo) |
           ((unsigned int)(unsigned short)bfs(hi) << 16);
}

// XOR swizzle on 8-element granularity (bits 3..5) — breaks the 128B-row-stride
// bank pattern for cbf's ds_read_b128; 2-way residual conflict is free (m136).
#define SWZ(r, k) ((k) ^ (((r) & 7) << 3))

// ---------------- prep: one-time (per call) constant conversion into ws ----------------
__global__ __launch_bounds__(256) void prep_kernel(
    const float* __restrict__ W, const float* __restrict__ bvec,
    const float* __restrict__ gamma, const float* __restrict__ leaf,
    unsigned char* __restrict__ ws)
{
    unsigned short* wbf = (unsigned short*)(ws + WS_WBF);
    unsigned short* lT  = (unsigned short*)(ws + WS_LEAFT);
    float* bias = (float*)(ws + WS_BIAS);
    float* g0v  = (float*)(ws + WS_GSM0);
    float* g1v  = (float*)(ws + WS_GSM1);
    const int tid  = blockIdx.x * 256 + threadIdx.x;
    const int nthr = gridDim.x * 256;

    for (int i = tid; i < 64 * INDIM; i += nthr) {          // W -> bf16, pad rows 62,63
        int r = i >> 9;
        float v = (r < 62) ? W[i] : 0.0f;                    // W is [31][2][512] == [62][512]
        wbf[i] = (unsigned short)bfs(v);
    }
    for (int i = tid; i < OUTDIM * 64; i += nthr) {          // leaf^T -> bf16 [col][node]
        int n = i & 63, col = i >> 6;
        float v = (n < 63) ? leaf[(size_t)n * OUTDIM + col] : 0.0f;
        lT[i] = (unsigned short)bfs(v);
    }
    if (tid < 64) bias[tid] = (tid < 62) ? bvec[tid] : 0.0f;
    if (tid < NINT) {
        float a = gamma[2*tid], b = gamma[2*tid+1];
        float m = fmaxf(a, b);
        float e0 = __expf(a - m), e1 = __expf(b - m);
        float inv = 1.0f / (e0 + e1);
        g0v[tid] = e0 * inv;
        g1v[tid] = e1 * inv;
    }
}

// ---------------- main: logits (direct-global MFMA) -> tree walk -> out GEMM ----------------
__global__ __launch_bounds__(THREADS) void mix_main(
    const float* __restrict__ x, const unsigned char* __restrict__ ws,
    float* __restrict__ out)
{
    __shared__ __align__(16) float Lg[BM][65];              // +1 pad: conflict-free column walk
    __shared__ __align__(16) unsigned short cbf[BM][64];    // coefficients, bf16, XOR-swizzled

    const int t    = threadIdx.x;
    const int lane = t & 63;
    const int wv   = t >> 6;       // wave 0..3 -> rows 16wv..16wv+15
    const int g    = lane >> 4;    // k-slot group
    const int lm   = lane & 15;
    const int row0 = blockIdx.x * BM;

    // bias folded into accumulator init (acc[c][r] = b[col], col = 16c+lm)
    const float* bias = (const float*)(ws + WS_BIAS);
    f4v acc[4];
    #pragma unroll
    for (int c = 0; c < 4; ++c) {
        float b = bias[16*c + lm];
        acc[c] = (f4v){b, b, b, b};
    }

    // ---- P1: logits = x @ W^T + b, K fully unrolled, no LDS, no barriers ----
    const float* xrow = x + (size_t)(row0 + 16*wv + lm) * INDIM;
    const unsigned short* wb = (const unsigned short*)(ws + WS_WBF);
    #pragma unroll
    for (int ks = 0; ks < INDIM / 32; ++ks) {
        const int k0 = ks * 32 + 8 * g;
        float4 x0 = *(const float4*)(xrow + k0);
        float4 x1 = *(const float4*)(xrow + k0 + 4);
        s8v a;
        a[0] = bfs(x0.x); a[1] = bfs(x0.y); a[2] = bfs(x0.z); a[3] = bfs(x0.w);
        a[4] = bfs(x1.x); a[5] = bfs(x1.y); a[6] = bfs(x1.z); a[7] = bfs(x1.w);
        #pragma unroll
        for (int c = 0; c < 4; ++c) {
            s8v b = *(const s8v*)(wb + (size_t)(16*c + lm) * INDIM + k0);
            acc[c] = __builtin_amdgcn_mfma_f32_16x16x32_bf16(a, b, acc[c], 0, 0, 0);
        }
    }
    // C/D layout (HW-verified): col = lane&15, row = 4*(lane>>4) + reg
    #pragma unroll
    for (int c = 0; c < 4; ++c)
        #pragma unroll
        for (int r = 0; r < 4; ++r)
            Lg[16*wv + 4*g + r][16*c + lm] = acc[c][r];
    __syncthreads();

    // ---- P2: per-row tree walk (64 walkers), fully unrolled (static indexing) ----
    if (t < BM) {
        const int row = t;
        const float* g0v = (const float*)(ws + WS_GSM0);
        const float* g1v = (const float*)(ws + WS_GSM1);
        float Pp[63];
        float cv[64];
        Pp[0] = 1.0f;
        #pragma unroll
        for (int n = 0; n < NINT; ++n) {
            float l0 = Lg[row][2*n];
            float l1 = Lg[row][2*n + 1];
            float r1 = 1.0f / (1.0f + __expf(l0 - l1));      // softmax pair, overflow-safe
            float base = Pp[n] * g0v[n];
            Pp[2*n + 1] = base * (1.0f - r1);
            Pp[2*n + 2] = base * r1;
            cv[n] = Pp[n] * g1v[n];
        }
        #pragma unroll
        for (int n = NINT; n < 63; ++n) cv[n] = Pp[n];
        cv[63] = 0.0f;                                       // pad node
        #pragma unroll
        for (int c2 = 0; c2 < 8; ++c2) {
            int p = SWZ(row, 8 * c2);
            *(uint4*)&cbf[row][p] = make_uint4(
                pk2(cv[8*c2+0], cv[8*c2+1]), pk2(cv[8*c2+2], cv[8*c2+3]),
                pk2(cv[8*c2+4], cv[8*c2+5]), pk2(cv[8*c2+6], cv[8*c2+7]));
        }
    }
    __syncthreads();

    // ---- P3: Out[64][128] = C @ leaf (K=64), leaf^T bf16 straight from L2 ----
    const unsigned short* lT = (const unsigned short*)(ws + WS_LEAFT);
    f4v o[8] = {};
    #pragma unroll
    for (int kw = 0; kw < 2; ++kw) {
        const int k0 = kw * 32 + 8 * g;
        s8v a = *(const s8v*)&cbf[16*wv + lm][SWZ(lm, k0)];  // (16wv+lm)&7 == lm&7
        #pragma unroll
        for (int nt = 0; nt < 8; ++nt) {
            s8v b = *(const s8v*)(lT + (size_t)(16*nt + lm) * 64 + k0);
            o[nt] = __builtin_amdgcn_mfma_f32_16x16x32_bf16(a, b, o[nt], 0, 0, 0);
        }
    }
    #pragma unroll
    for (int nt = 0; nt < 8; ++nt)
        #pragma unroll
        for (int r = 0; r < 4; ++r)
            out[(size_t)(row0 + 16*wv + 4*g + r) * OUTDIM + 16*nt + lm] = o[nt][r];
}

extern "C" void kernel_launch(void* const* d_in, const int* in_sizes, int n_in,
                              void* d_out, int out_size, void* d_ws, size_t ws_size,
                              hipStream_t stream) {
    const float* x     = (const float*)d_in[0];
    const float* W     = (const float*)d_in[1];
    const float* b     = (const float*)d_in[2];
    const float* gamma = (const float*)d_in[3];
    const float* leaf  = (const float*)d_in[4];
    float* out = (float*)d_out;
    hipLaunchKernelGGL(prep_kernel, dim3(64), dim3(256), 0, stream,
                       W, b, gamma, leaf, (unsigned char*)d_ws);
    hipLaunchKernelGGL(mix_main, dim3(BATCH / BM), dim3(THREADS), 0, stream,
                       x, (const unsigned char*)d_ws, out);
}